// Round 8
// baseline (275.091 us; speedup 1.0000x reference)
//
#include <hip/hip_runtime.h>
#include <hip/hip_bf16.h>

#define NN 50000
#define NE 800000

typedef __attribute__((ext_vector_type(8))) short short8;            // 8 bf16
typedef __attribute__((ext_vector_type(8))) unsigned short ushort8;  // 16 B
typedef __attribute__((ext_vector_type(4))) float f32x4;

static __device__ __forceinline__ unsigned short f2bf(float x) {
    unsigned u = __float_as_uint(x);
    unsigned r = (u + 0x7fffu + ((u >> 16) & 1u)) >> 16;   // RNE
    return (unsigned short)r;
}
static __device__ __forceinline__ float bf2f(unsigned short s) {
    return __uint_as_float(((unsigned)s) << 16);
}

// ---------------------------------------------------------------------------
// Kernel 1: fused QKV GEMM (bf16x3 split-precision MFMA) + edge histogram.
// y=0..2: 128x128 tile, 4 waves 2x2, 4x4 tiles of 16x16x32 MFMA each.
// Epilogue: y==0 -> fp32 qbuf; y==1/2 (k/v) -> bf16 kvbuf with k/v channel-
// interleaved rows: kvrow[(c>>2)*8 + (c&3) + (isK?0:4)] — so node_attn reads
// one b128 per lane per edge (k half + v half together).
// y==3: grid-stride degree histogram (overlaps GEMM).
// ---------------------------------------------------------------------------
__global__ __launch_bounds__(256) void qkv_gemm(
    const float* __restrict__ feat, const float* __restrict__ w,
    const float* __restrict__ bias, float* __restrict__ qbuf,
    unsigned short* __restrict__ kvbuf,
    const int* __restrict__ graph, int* __restrict__ deg)
{
    if (blockIdx.y == 3) {          // histogram path (uniform per block)
        int stride = gridDim.x * 256;
        for (int e = blockIdx.x * 256 + threadIdx.x; e < NE; e += stride)
            atomicAdd(&deg[graph[e]], 1);
        return;
    }

    __shared__ __align__(16) short Ah[128][40];
    __shared__ __align__(16) short Al[128][40];
    __shared__ __align__(16) short Bh[128][40];
    __shared__ __align__(16) short Bl[128][40];

    const int t  = threadIdx.x;
    const int bm = blockIdx.x * 128;
    const int bc = blockIdx.y * 128;

    const int wave = t >> 6;
    const int lane = t & 63;
    const int wr = wave & 1;
    const int wc = wave >> 1;
    const int qd = lane >> 4;
    const int l15 = lane & 15;

    f32x4 acc[4][4];
#pragma unroll
    for (int i = 0; i < 4; ++i)
#pragma unroll
        for (int j = 0; j < 4; ++j)
            acc[i][j] = (f32x4){0.f, 0.f, 0.f, 0.f};

    for (int ks = 0; ks < 4; ++ks) {
        const int k0 = ks * 32;
        if (ks) __syncthreads();
#pragma unroll
        for (int i = 0; i < 4; ++i) {
            int idx = i * 256 + t;
            int r  = idx >> 3;
            int c4 = (idx & 7) * 4;
            int ga = bm + r;
            float4 a4 = (ga < NN)
                ? *(const float4*)(feat + (size_t)ga * 128 + k0 + c4)
                : make_float4(0.f, 0.f, 0.f, 0.f);
            float4 b4 = *(const float4*)(w + (size_t)(bc + r) * 128 + k0 + c4);
            unsigned short h;
            short4 hv, lv;
            h = f2bf(a4.x); hv.x = (short)h; lv.x = (short)f2bf(a4.x - bf2f(h));
            h = f2bf(a4.y); hv.y = (short)h; lv.y = (short)f2bf(a4.y - bf2f(h));
            h = f2bf(a4.z); hv.z = (short)h; lv.z = (short)f2bf(a4.z - bf2f(h));
            h = f2bf(a4.w); hv.w = (short)h; lv.w = (short)f2bf(a4.w - bf2f(h));
            *(short4*)&Ah[r][c4] = hv;
            *(short4*)&Al[r][c4] = lv;
            h = f2bf(b4.x); hv.x = (short)h; lv.x = (short)f2bf(b4.x - bf2f(h));
            h = f2bf(b4.y); hv.y = (short)h; lv.y = (short)f2bf(b4.y - bf2f(h));
            h = f2bf(b4.z); hv.z = (short)h; lv.z = (short)f2bf(b4.z - bf2f(h));
            h = f2bf(b4.w); hv.w = (short)h; lv.w = (short)f2bf(b4.w - bf2f(h));
            *(short4*)&Bh[r][c4] = hv;
            *(short4*)&Bl[r][c4] = lv;
        }
        __syncthreads();
        short8 ah[4], al[4];
#pragma unroll
        for (int i = 0; i < 4; ++i) {
            ah[i] = *(const short8*)&Ah[wr * 64 + 16 * i + l15][qd * 8];
            al[i] = *(const short8*)&Al[wr * 64 + 16 * i + l15][qd * 8];
        }
#pragma unroll
        for (int j = 0; j < 4; ++j) {
            short8 bh = *(const short8*)&Bh[wc * 64 + 16 * j + l15][qd * 8];
            short8 bl = *(const short8*)&Bl[wc * 64 + 16 * j + l15][qd * 8];
#pragma unroll
            for (int i = 0; i < 4; ++i) {
                acc[i][j] = __builtin_amdgcn_mfma_f32_16x16x32_bf16(al[i], bh, acc[i][j], 0, 0, 0);
                acc[i][j] = __builtin_amdgcn_mfma_f32_16x16x32_bf16(ah[i], bl, acc[i][j], 0, 0, 0);
                acc[i][j] = __builtin_amdgcn_mfma_f32_16x16x32_bf16(ah[i], bh, acc[i][j], 0, 0, 0);
            }
        }
    }

    float bj[4];
#pragma unroll
    for (int j = 0; j < 4; ++j)
        bj[j] = bias[bc + wc * 64 + 16 * j + l15];

    const int isQ = (blockIdx.y == 0);
    const int vofs = (blockIdx.y == 1) ? 0 : 4;   // k half vs v half of 8-group
#pragma unroll
    for (int i = 0; i < 4; ++i) {
#pragma unroll
        for (int rg = 0; rg < 4; ++rg) {
            int row = bm + wr * 64 + 16 * i + qd * 4 + rg;
            if (row >= NN) continue;
#pragma unroll
            for (int j = 0; j < 4; ++j) {
                float v = acc[i][j][rg] + bj[j];
                int col = wc * 64 + 16 * j + l15;
                if (isQ) qbuf[(size_t)row * 128 + col] = v;
                else     kvbuf[(size_t)row * 256 + (col >> 2) * 8 + (col & 3) + vofs] = f2bf(v);
            }
        }
    }
}

// ---------------------------------------------------------------------------
// CSR offsets + per-node RPE constants:
//   ca[n][h] = c[n].rw_sum[h]          (src-side term)
//   cb[n][h] = ca[n][h] + rb_sum[h]    (dst-side term)
// so per-edge rpe = cb[dst][h] - ca[src][h].
// ---------------------------------------------------------------------------
__global__ __launch_bounds__(256) void k_offsets(
    const int* __restrict__ deg, int* __restrict__ row_start,
    int* __restrict__ cursor, int* __restrict__ counter,
    const float* __restrict__ coord, const float* __restrict__ rpe_w,
    const float* __restrict__ rpe_b, float* __restrict__ ca,
    float* __restrict__ cb)
{
    __shared__ float s_rw[12];
    __shared__ float s_rb[4];
    if (threadIdx.x < 12) {
        int h = threadIdx.x / 3, p = threadIdx.x % 3;
        float s = 0.f;
        for (int d = 0; d < 32; ++d) s += rpe_w[(h * 32 + d) * 3 + p];
        s_rw[threadIdx.x] = s;
    } else if (threadIdx.x < 16) {
        int h = threadIdx.x - 12;
        float s = 0.f;
        for (int d = 0; d < 32; ++d) s += rpe_b[h * 32 + d];
        s_rb[h] = s;
    }
    __syncthreads();

    int n = blockIdx.x * 256 + threadIdx.x;
    int lane = threadIdx.x & 63;
    int d = (n < NN) ? deg[n] : 0;
    int x = d;
#pragma unroll
    for (int off = 1; off < 64; off <<= 1) {
        int y = __shfl_up(x, off);
        if (lane >= off) x += y;
    }
    int wave_base = 0;
    if (lane == 63) wave_base = atomicAdd(counter, x);
    wave_base = __shfl(wave_base, 63);
    if (n < NN) {
        int s = wave_base + x - d;
        row_start[n] = s;
        cursor[n] = s;
        float c0 = coord[n * 3 + 0], c1 = coord[n * 3 + 1], c2 = coord[n * 3 + 2];
#pragma unroll
        for (int h = 0; h < 4; ++h) {
            float a = c0 * s_rw[h * 3 + 0] + c1 * s_rw[h * 3 + 1] + c2 * s_rw[h * 3 + 2];
            ca[n * 4 + h] = a;
            cb[n * 4 + h] = a + s_rb[h];
        }
    }
}

__global__ __launch_bounds__(256) void k_scatter(
    const int* __restrict__ graph, int* __restrict__ cursor,
    int* __restrict__ sorted_src)
{
    int e = blockIdx.x * 256 + threadIdx.x;
    if (e < NE) {
        int dst = graph[e];
        int src = graph[NE + e];
        int slot = atomicAdd(&cursor[dst], 1);
        sorted_src[slot] = src;
    }
}

// ---------------------------------------------------------------------------
// Kernel 2: per-node attention. 32 lanes/node, one b128 interleaved k/v load
// per lane per edge, broadcast ca[src][h] dword, __expf, 4x unroll.
// ---------------------------------------------------------------------------
__global__ __launch_bounds__(256) void node_attn(
    const float* __restrict__ qbuf, const unsigned short* __restrict__ kvbuf,
    const float* __restrict__ ca, const float* __restrict__ cb,
    const int* __restrict__ row_start, const int* __restrict__ deg,
    const int* __restrict__ sorted_src, float* __restrict__ out)
{
    const int t = threadIdx.x;
    const int n = blockIdx.x * 8 + (t >> 5);
    if (n >= NN) return;
    const int j = t & 31;
    const int h = j >> 3;

    const float4 q4 = ((const float4*)(qbuf + (size_t)n * 128))[j];
    const float cbh = cb[n * 4 + h];
    const int start = row_start[n];
    const int d = deg[n];

    float4 acc = make_float4(0.f, 0.f, 0.f, 0.f);
    float den = 0.f;
    const ushort8* kvb = (const ushort8*)kvbuf;   // 32 x ushort8 per row

    int i = 0;
    for (; i + 3 < d; i += 4) {
        int s0 = sorted_src[start + i];
        int s1 = sorted_src[start + i + 1];
        int s2 = sorted_src[start + i + 2];
        int s3 = sorted_src[start + i + 3];
        ushort8 u0 = kvb[(size_t)s0 * 32 + j];
        ushort8 u1 = kvb[(size_t)s1 * 32 + j];
        ushort8 u2 = kvb[(size_t)s2 * 32 + j];
        ushort8 u3 = kvb[(size_t)s3 * 32 + j];
        float a0 = ca[s0 * 4 + h], a1 = ca[s1 * 4 + h];
        float a2 = ca[s2 * 4 + h], a3 = ca[s3 * 4 + h];

        float p0 = q4.x * bf2f(u0[0]) + q4.y * bf2f(u0[1]) + q4.z * bf2f(u0[2]) + q4.w * bf2f(u0[3]);
        float p1 = q4.x * bf2f(u1[0]) + q4.y * bf2f(u1[1]) + q4.z * bf2f(u1[2]) + q4.w * bf2f(u1[3]);
        float p2 = q4.x * bf2f(u2[0]) + q4.y * bf2f(u2[1]) + q4.z * bf2f(u2[2]) + q4.w * bf2f(u2[3]);
        float p3 = q4.x * bf2f(u3[0]) + q4.y * bf2f(u3[1]) + q4.z * bf2f(u3[2]) + q4.w * bf2f(u3[3]);
        p0 += __shfl_xor(p0, 1); p1 += __shfl_xor(p1, 1);
        p2 += __shfl_xor(p2, 1); p3 += __shfl_xor(p3, 1);
        p0 += __shfl_xor(p0, 2); p1 += __shfl_xor(p1, 2);
        p2 += __shfl_xor(p2, 2); p3 += __shfl_xor(p3, 2);
        p0 += __shfl_xor(p0, 4); p1 += __shfl_xor(p1, 4);
        p2 += __shfl_xor(p2, 4); p3 += __shfl_xor(p3, 4);

        float e0 = __expf(p0 + cbh - a0);
        float e1 = __expf(p1 + cbh - a1);
        float e2 = __expf(p2 + cbh - a2);
        float e3 = __expf(p3 + cbh - a3);
        den += (e0 + e1) + (e2 + e3);
        acc.x += e0 * bf2f(u0[4]) + e1 * bf2f(u1[4]) + e2 * bf2f(u2[4]) + e3 * bf2f(u3[4]);
        acc.y += e0 * bf2f(u0[5]) + e1 * bf2f(u1[5]) + e2 * bf2f(u2[5]) + e3 * bf2f(u3[5]);
        acc.z += e0 * bf2f(u0[6]) + e1 * bf2f(u1[6]) + e2 * bf2f(u2[6]) + e3 * bf2f(u3[6]);
        acc.w += e0 * bf2f(u0[7]) + e1 * bf2f(u1[7]) + e2 * bf2f(u2[7]) + e3 * bf2f(u3[7]);
    }
    for (; i < d; ++i) {
        int s0 = sorted_src[start + i];
        ushort8 u0 = kvb[(size_t)s0 * 32 + j];
        float a0 = ca[s0 * 4 + h];
        float p0 = q4.x * bf2f(u0[0]) + q4.y * bf2f(u0[1]) + q4.z * bf2f(u0[2]) + q4.w * bf2f(u0[3]);
        p0 += __shfl_xor(p0, 1);
        p0 += __shfl_xor(p0, 2);
        p0 += __shfl_xor(p0, 4);
        float e0 = __expf(p0 + cbh - a0);
        den += e0;
        acc.x += e0 * bf2f(u0[4]); acc.y += e0 * bf2f(u0[5]);
        acc.z += e0 * bf2f(u0[6]); acc.w += e0 * bf2f(u0[7]);
    }

    float inv = (den > 0.f) ? 1.0f / den : 0.f;
    float4 o = make_float4(acc.x * inv, acc.y * inv, acc.z * inv, acc.w * inv);
    ((float4*)(out + (size_t)n * 128))[j] = o;
}

extern "C" void kernel_launch(void* const* d_in, const int* in_sizes, int n_in,
                              void* d_out, int out_size, void* d_ws, size_t ws_size,
                              hipStream_t stream) {
    const float* feat  = (const float*)d_in[0];
    const float* coord = (const float*)d_in[1];
    const int*   graph = (const int*)d_in[2];
    const float* qkv_w = (const float*)d_in[3];
    const float* qkv_b = (const float*)d_in[4];
    const float* rpe_w = (const float*)d_in[5];
    const float* rpe_b = (const float*)d_in[6];
    float* out = (float*)d_out;

    float*          qbuf  = (float*)d_ws;                                // NN x 128 f32
    unsigned short* kvbuf = (unsigned short*)(qbuf + (size_t)NN * 128);  // NN x 256 bf16
    int* deg        = (int*)(kvbuf + (size_t)NN * 256);
    int* row_start  = deg + NN;
    int* cursor     = row_start + NN;
    int* counter    = cursor + NN;
    int* sorted_src = counter + 1;
    float* ca       = (float*)(sorted_src + NE);   // NN x 4
    float* cb       = ca + (size_t)NN * 4;         // NN x 4

    hipMemsetAsync(deg, 0, NN * sizeof(int), stream);
    hipMemsetAsync(counter, 0, sizeof(int), stream);

    qkv_gemm <<<dim3(391, 4), 256, 0, stream>>>(feat, qkv_w, qkv_b, qbuf, kvbuf,
                                                graph, deg);
    k_offsets<<<dim3((NN + 255) / 256), 256, 0, stream>>>(deg, row_start, cursor, counter,
                                                          coord, rpe_w, rpe_b, ca, cb);
    k_scatter<<<dim3((NE + 255) / 256), 256, 0, stream>>>(graph, cursor, sorted_src);
    node_attn<<<dim3((NN + 7) / 8), 256, 0, stream>>>(qbuf, kvbuf, ca, cb,
                                                      row_start, deg, sorted_src, out);
}